// Round 7
// baseline (784.449 us; speedup 1.0000x reference)
//
#include <hip/hip_runtime.h>

#define B_    256
#define L_    200
#define EMB_  128
#define HD_   64
#define HCN_  1000
#define POI_  20000
#define EPS_  1e-8f
#define CP    224          // padded L for c / ut k-dim (7 chunks of 32)
#define UNR   208          // umap-native rows (l), rows 200..207 zero

// power-of-2 pre-scales keep fp16 second-splits in the normal range
#define CSC   16384.0f     // c scale (2^14)
#define USC   256.0f       // umap scale (2^8)
#define VSC   1024.0f      // v scale (2^10)
#define SV_DESC (1.0f / (CSC * USC))   // 2^-22, exact
#define UV_DESC (1.0f / (VSC * USC))   // 2^-18, exact

typedef _Float16 half8 __attribute__((ext_vector_type(8)));
typedef __bf16  bf16x8 __attribute__((ext_vector_type(8)));
typedef float   f32x4  __attribute__((ext_vector_type(4)));
typedef float   f32x16 __attribute__((ext_vector_type(16)));

__device__ __forceinline__ unsigned short f2bf(float f) {
  union { float f; unsigned int u; } v; v.f = f;
  unsigned int r = (v.u + 0x7FFFu + ((v.u >> 16) & 1u)) >> 16;  // RNE
  return (unsigned short)r;
}
// 2-way fp16 split of a PRE-SCALED value: x ~= s1+s2 to ~2^-22 relative
__device__ __forceinline__ void split2h(float x, _Float16& s1, _Float16& s2) {
  s1 = (_Float16)x;
  s2 = (_Float16)(x - (float)s1);
}

// 4-pass split product (keeps all cross terms; small-first accumulation)
#define FOURPASS(acc, A1f, A2f, B1f, B2f)                                  \
  acc = __builtin_amdgcn_mfma_f32_16x16x32_f16(A2f, B2f, acc, 0, 0, 0);    \
  acc = __builtin_amdgcn_mfma_f32_16x16x32_f16(A2f, B1f, acc, 0, 0, 0);    \
  acc = __builtin_amdgcn_mfma_f32_16x16x32_f16(A1f, B2f, acc, 0, 0, 0);    \
  acc = __builtin_amdgcn_mfma_f32_16x16x32_f16(A1f, B1f, acc, 0, 0, 0);

// ---------------------------------------------------------------------------
// k_umap: u_map[b,l,:] = u[b,l,:] @ l_map_h  (fp32 — routing precision source)
__global__ __launch_bounds__(256) void k_umap(const float* __restrict__ u,
                                              const float* __restrict__ lmap,
                                              float* __restrict__ umap) {
  __shared__ __align__(16) float lm[EMB_ * HD_];   // 32 KB
  for (int i = threadIdx.x; i < EMB_ * HD_; i += 256) lm[i] = lmap[i];
  __syncthreads();
  const int wave = threadIdx.x >> 6, lane = threadIdx.x & 63;
  const int wid = blockIdx.x * 4 + wave;
  for (int row = wid; row < B_ * L_; row += 3200) {
    const float* ur = u + (size_t)row * EMB_;
    float a0 = ur[lane];
    float a1 = ur[lane + 64];
    float acc = 0.f;
#pragma unroll
    for (int k = 0; k < 64; ++k)
      acc = fmaf(__shfl(a0, k), lm[k * HD_ + lane], acc);
#pragma unroll
    for (int k = 0; k < 64; ++k)
      acc = fmaf(__shfl(a1, k), lm[(k + 64) * HD_ + lane], acc);
    umap[(size_t)row * HD_ + lane] = acc;
  }
}

// ---------------------------------------------------------------------------
// k_prep2: umap[b] fp32 -> fp16 2-splits of (umap*USC), native [b][208][64]
// (rows 200..207 zero) and transposed [b][64][224] (cols 200..223 zero).
__global__ __launch_bounds__(256) void k_prep2(const float* __restrict__ umap,
    _Float16* __restrict__ un1, _Float16* __restrict__ un2,
    _Float16* __restrict__ ut1, _Float16* __restrict__ ut2) {
  __shared__ __align__(16) float us[CP][68];   // 60.9 KB
  const int b = blockIdx.x;
  const float* ub = umap + (size_t)b * L_ * HD_;
  for (int i = threadIdx.x; i < CP * HD_; i += 256) {
    int l = i >> 6, d = i & 63;
    us[l][d] = (l < L_) ? ub[l * HD_ + d] * USC : 0.f;
  }
  __syncthreads();
  // native: (row 208, oct 8)
  for (int s = threadIdx.x; s < UNR * 8; s += 256) {
    int row = s >> 3, oct = s & 7;
    _Float16 t1[8], t2[8];
#pragma unroll
    for (int j = 0; j < 8; ++j) split2h(us[row][oct * 8 + j], t1[j], t2[j]);
    size_t dst = ((size_t)b * UNR + row) * HD_ + oct * 8;
    *(uint4*)&un1[dst] = *(uint4*)t1;
    *(uint4*)&un2[dst] = *(uint4*)t2;
  }
  // transposed: (d 64, l-oct 28)
  for (int s = threadIdx.x; s < HD_ * 28; s += 256) {
    int d = s / 28, lo8 = s % 28;
    _Float16 t1[8], t2[8];
#pragma unroll
    for (int j = 0; j < 8; ++j) split2h(us[lo8 * 8 + j][d], t1[j], t2[j]);
    size_t dst = ((size_t)b * HD_ + d) * CP + lo8 * 8;
    *(uint4*)&ut1[dst] = *(uint4*)t1;
    *(uint4*)&ut2[dst] = *(uint4*)t2;
  }
}

// ---------------------------------------------------------------------------
// k_softmax2: (SUM) b[row,:] += sum_bg part[bg][row,:], write back; then
// c[row,:] = softmax(b[row,:]) -> fp16 2-splits of (c*CSC), [1024][224];
// rows 1000..1023 and cols 200..223 exact zero.
template<int SUM>
__global__ __launch_bounds__(256) void k_softmax2(float* __restrict__ bl,
    const float* __restrict__ part,
    _Float16* __restrict__ c1, _Float16* __restrict__ c2) {
  const int wave = threadIdx.x >> 6, lane = threadIdx.x & 63;
  const int row = blockIdx.x * 4 + wave;                 // 0..1023
  const size_t rb = (size_t)row * CP;
  if (row >= HCN_) {
    c1[rb + lane] = (_Float16)0.f;       c2[rb + lane] = (_Float16)0.f;
    c1[rb + lane + 64] = (_Float16)0.f;  c2[rb + lane + 64] = (_Float16)0.f;
    c1[rb + lane + 128] = (_Float16)0.f; c2[rb + lane + 128] = (_Float16)0.f;
    if (lane < 32) { c1[rb + 192 + lane] = (_Float16)0.f; c2[rb + 192 + lane] = (_Float16)0.f; }
    return;
  }
  float* br = bl + (size_t)row * L_;
  float x0 = br[lane];
  float x1 = br[lane + 64];
  float x2 = br[lane + 128];
  float x3 = (lane < 8) ? br[lane + 192] : -3.0e38f;
  if (SUM) {
    const float* pr = part + (size_t)row * L_;
#pragma unroll 4
    for (int g = 0; g < 32; ++g) {
      const float* p = pr + (size_t)g * HCN_ * L_;
      x0 += p[lane];
      x1 += p[lane + 64];
      x2 += p[lane + 128];
      if (lane < 8) x3 += p[lane + 192];
    }
    // persist updated logits for the next iteration
    br[lane] = x0; br[lane + 64] = x1; br[lane + 128] = x2;
    if (lane < 8) br[lane + 192] = x3;
  }
  float m = fmaxf(fmaxf(x0, x1), fmaxf(x2, x3));
#pragma unroll
  for (int off = 32; off; off >>= 1) m = fmaxf(m, __shfl_xor(m, off));
  float e0 = expf(x0 - m), e1 = expf(x1 - m), e2 = expf(x2 - m);
  float e3 = (lane < 8) ? expf(x3 - m) : 0.f;
  float ssum = e0 + e1 + e2 + e3;
#pragma unroll
  for (int off = 32; off; off >>= 1) ssum += __shfl_xor(ssum, off);
  float inv = CSC / ssum;
  _Float16 s1, s2;
  split2h(e0 * inv, s1, s2); c1[rb + lane] = s1;       c2[rb + lane] = s2;
  split2h(e1 * inv, s1, s2); c1[rb + lane + 64] = s1;  c2[rb + lane + 64] = s2;
  split2h(e2 * inv, s1, s2); c1[rb + lane + 128] = s1; c2[rb + lane + 128] = s2;
  if (lane < 8) {
    split2h(e3 * inv, s1, s2); c1[rb + 192 + lane] = s1; c2[rb + 192 + lane] = s2;
  } else if (lane < 32) {
    c1[rb + 192 + lane] = (_Float16)0.f; c2[rb + 192 + lane] = (_Float16)0.f;
  }
}

// ---------------------------------------------------------------------------
// k_iter: fused routing iteration, fp16 2-split / 4-pass, pre-scaled.
// Per block: 8 batches x 64 h-rows. B-operand fragments are loaded DIRECTLY
// from global (per-lane 16B, L2-resident via bg-pinned XCD swizzle) — no LDS
// staging, no staging barriers. Only v transpose uses LDS (2-buf, 1 barrier
// per batch). UV partials go to part[bg] (plain stores, no atomics).
// Grid 512: bg = id&31 (id%8 = bg%8 -> all 16 ht-blocks of a bg on one XCD).
template<int UV, int HOUT>
__global__ __launch_bounds__(256, 2) void k_iter(
    const _Float16* __restrict__ c1p, const _Float16* __restrict__ c2p,
    const _Float16* __restrict__ un1, const _Float16* __restrict__ un2,
    const _Float16* __restrict__ ut1, const _Float16* __restrict__ ut2,
    const float* __restrict__ wdim, const float* __restrict__ bdim,
    float* __restrict__ part, float* __restrict__ h) {
  __shared__ __align__(16) _Float16 v_s[2][2][64][72];   // 36,864 B (2-buf)

  const int id = blockIdx.x;
  const int bg = id & 31;          // XCD = bg%8: read locality for un/ut[b]
  const int ht = id >> 5;          // 0..15
  const int h0 = ht * 64;
  const int b0 = bg * 8;
  const int tid = threadIdx.x;
  const int wave = tid >> 6, lane = tid & 63;
  const int l15 = lane & 15, oc = lane >> 4;
  const int rowA = h0 + wave * 16 + l15;     // A-frag row (c row / v row)
  const int rowC = h0 + wave * 16 + oc * 4;  // C/D row base (+r)

  // hoisted A fragments (c rows; invariant over the 8 batches)
  half8 a_f[7][2];
#pragma unroll
  for (int ck = 0; ck < 7; ++ck) {
    const size_t off = (size_t)rowA * CP + ck * 32 + oc * 8;
    a_f[ck][0] = *(const half8*)&c1p[off];
    a_f[ck][1] = *(const half8*)&c2p[off];
  }

  f32x4 acc_uv[13];
  if (UV) {
#pragma unroll
    for (int nt = 0; nt < 13; ++nt) acc_uv[nt] = (f32x4){0.f, 0.f, 0.f, 0.f};
  }
  float wd[4] = {0.f, 0.f, 0.f, 0.f};
  float bd = 0.f;
  if (HOUT) {
#pragma unroll
    for (int nt = 0; nt < 4; ++nt) wd[nt] = wdim[nt * 16 + l15];
    bd = bdim[0];
  }

  for (int bi = 0; bi < 8; ++bi) {
    const int b = b0 + bi;
    // ---------------- SV: s = c @ umap[b] (scaled 2^22) ----------------
    // B-frags direct from ut (row = d = nt*16+l15, k = ck*32+oc*8)
    f32x4 acc_s[4];
#pragma unroll
    for (int nt = 0; nt < 4; ++nt) acc_s[nt] = (f32x4){0.f, 0.f, 0.f, 0.f};
#pragma unroll
    for (int ck = 0; ck < 7; ++ck) {
#pragma unroll
      for (int nt = 0; nt < 4; ++nt) {
        const size_t bo = ((size_t)b * HD_ + nt * 16 + l15) * CP + ck * 32 + oc * 8;
        const half8 b1 = *(const half8*)&ut1[bo];
        const half8 b2 = *(const half8*)&ut2[bo];
        FOURPASS(acc_s[nt], a_f[ck][0], a_f[ck][1], b1, b2);
      }
    }
    // ---------------- squash (in-register, descaled) ----------------
    float xdesc[4][4];   // [nt][r]
#pragma unroll
    for (int nt = 0; nt < 4; ++nt)
#pragma unroll
      for (int r = 0; r < 4; ++r) xdesc[nt][r] = acc_s[nt][r] * SV_DESC;
    float gg[4];
#pragma unroll
    for (int r = 0; r < 4; ++r) {
      float sq = 0.f, hpp = 0.f;
#pragma unroll
      for (int nt = 0; nt < 4; ++nt) {
        float x = xdesc[nt][r];
        sq += x * x;
        if (HOUT) hpp += x * wd[nt];
      }
#pragma unroll
      for (int off = 8; off; off >>= 1) {
        sq += __shfl_xor(sq, off);
        if (HOUT) hpp += __shfl_xor(hpp, off);
      }
      gg[r] = sq / ((1.f + sq) * sqrtf(sq + EPS_));
      if (HOUT && l15 == 0 && rowC + r < HCN_)
        h[(size_t)b * HCN_ + rowC + r] = gg[r] * hpp + bd;
    }
    // ---------------- UV: acc_uv += v @ umap[b]^T ----------------
    if (UV) {
      const int cur = bi & 1;
#pragma unroll
      for (int nt = 0; nt < 4; ++nt)
#pragma unroll
        for (int r = 0; r < 4; ++r) {
          _Float16 s1, s2;
          split2h(VSC * gg[r] * xdesc[nt][r], s1, s2);
          const int vr = wave * 16 + oc * 4 + r, vc = nt * 16 + l15;
          v_s[cur][0][vr][vc] = s1; v_s[cur][1][vr][vc] = s2;
        }
      __syncthreads();   // one barrier per batch (2-buf covers prev readers)
#pragma unroll
      for (int half = 0; half < 2; ++half) {
        const int vo = half * 32 + oc * 8;
        const half8 av1 = *(const half8*)&v_s[cur][0][wave * 16 + l15][vo];
        const half8 av2 = *(const half8*)&v_s[cur][1][wave * 16 + l15][vo];
#pragma unroll
        for (int nt = 0; nt < 13; ++nt) {
          const size_t bo = ((size_t)b * UNR + nt * 16 + l15) * HD_ + half * 32 + oc * 8;
          const half8 b1 = *(const half8*)&un1[bo];
          const half8 b2 = *(const half8*)&un2[bo];
          FOURPASS(acc_uv[nt], av1, av2, b1, b2);
        }
      }
    }
  }
  if (UV) {
    // plain stores into this bg's private partial slab (no atomics)
    float* pp = part + (size_t)bg * HCN_ * L_;
#pragma unroll
    for (int nt = 0; nt < 13; ++nt)
#pragma unroll
      for (int r = 0; r < 4; ++r) {
        const int row = rowC + r, l = nt * 16 + l15;
        if (row < HCN_ && l < L_)
          pp[(size_t)row * L_ + l] = acc_uv[nt][r] * UV_DESC;
      }
  }
}

// ---------------------------------------------------------------------------
// k_hcvt: h fp32 [256][1000] -> h_bf16 [256][1024] (zero-padded K tail)
__global__ __launch_bounds__(256) void k_hcvt(const float* __restrict__ h,
                                              unsigned short* __restrict__ hb) {
  const int row = blockIdx.x;
  for (int k = threadIdx.x; k < 1024; k += 256) {
    float val = (k < HCN_) ? h[row * HCN_ + k] : 0.f;
    hb[row * 1024 + k] = f2bf(val);
  }
}

// ---------------------------------------------------------------------------
// k_out_mfma: out[b,p] = sum_h h[b,h]*w_part[p,h] + b_part[p]  via bf16 MFMA.
#define KPAD 1024
#define LPITCH 72
__global__ __launch_bounds__(512) void k_out_mfma(const unsigned short* __restrict__ hb,
                                                  const float* __restrict__ wpart,
                                                  const float* __restrict__ bpart,
                                                  float* __restrict__ out) {
  __shared__ __align__(16) unsigned short w_lds[128 * LPITCH];  // 18432 B
  __shared__ __align__(16) unsigned short h_lds[128 * LPITCH];  // 18432 B
  const int p0 = blockIdx.x * 128;
  const int b0 = blockIdx.y * 128;
  const int t = threadIdx.x;
  const int wave = t >> 6, lane = t & 63;
  const int nt = wave & 3, mh = wave >> 2;
  const int l31 = lane & 31, lhi = lane >> 5;

  f32x16 acc0 = {};
  f32x16 acc1 = {};

  const int wrow = t >> 2;
  const int wq0  = (t & 3) * 4;
  int prow = p0 + wrow; if (prow > POI_ - 1) prow = POI_ - 1;
  const float* wrp = wpart + (size_t)prow * HCN_;

  for (int ch = 0; ch < 16; ++ch) {
    const int k0 = ch * 64;
    __syncthreads();
#pragma unroll
    for (int qq = 0; qq < 4; ++qq) {
      const int q = wq0 + qq;
      float4 wv;
      if (k0 + q * 4 + 3 < HCN_) {
        wv = *(const float4*)(wrp + k0 + q * 4);
      } else {
        float x0 = (k0 + q * 4 + 0 < HCN_) ? wrp[k0 + q * 4 + 0] : 0.f;
        float x1 = (k0 + q * 4 + 1 < HCN_) ? wrp[k0 + q * 4 + 1] : 0.f;
        float x2 = (k0 + q * 4 + 2 < HCN_) ? wrp[k0 + q * 4 + 2] : 0.f;
        float x3 = (k0 + q * 4 + 3 < HCN_) ? wrp[k0 + q * 4 + 3] : 0.f;
        wv = make_float4(x0, x1, x2, x3);
      }
      ushort4 bv;
      bv.x = f2bf(wv.x); bv.y = f2bf(wv.y); bv.z = f2bf(wv.z); bv.w = f2bf(wv.w);
      *(ushort4*)&w_lds[wrow * LPITCH + q * 4] = bv;
    }
#pragma unroll
    for (int n = 0; n < 2; ++n) {
      const int u = t + n * 512;
      const int hrow = u >> 3, hc = u & 7;
      const uint4 hv = *(const uint4*)(hb + (size_t)(b0 + hrow) * KPAD + k0 + hc * 8);
      *(uint4*)&h_lds[hrow * LPITCH + hc * 8] = hv;
    }
    __syncthreads();
#pragma unroll
    for (int ks = 0; ks < 4; ++ks) {
      const int kc = ks * 16 + lhi * 8;
      bf16x8 bfr = *(const bf16x8*)&w_lds[(nt * 32 + l31) * LPITCH + kc];
      bf16x8 a0  = *(const bf16x8*)&h_lds[(mh * 64 + 0 * 32 + l31) * LPITCH + kc];
      bf16x8 a1  = *(const bf16x8*)&h_lds[(mh * 64 + 1 * 32 + l31) * LPITCH + kc];
      acc0 = __builtin_amdgcn_mfma_f32_32x32x16_bf16(a0, bfr, acc0, 0, 0, 0);
      acc1 = __builtin_amdgcn_mfma_f32_32x32x16_bf16(a1, bfr, acc1, 0, 0, 0);
    }
  }

  const int p = p0 + nt * 32 + l31;
  const bool pok = (p < POI_);
  const float bp = pok ? bpart[p] : 0.f;
#pragma unroll
  for (int m = 0; m < 2; ++m) {
    const f32x16& a = m ? acc1 : acc0;
#pragma unroll
    for (int r = 0; r < 16; ++r) {
      const int brow = b0 + mh * 64 + m * 32 + (r & 3) + 8 * (r >> 2) + 4 * lhi;
      if (pok) out[(size_t)brow * POI_ + p] = a[r] + bp;
    }
  }
}

// ---------------------------------------------------------------------------
extern "C" void kernel_launch(void* const* d_in, const int* in_sizes, int n_in,
                              void* d_out, int out_size, void* d_ws, size_t ws_size,
                              hipStream_t stream) {
  const float* u     = (const float*)d_in[0];
  const float* lmap  = (const float*)d_in[1];
  const float* rw    = (const float*)d_in[2];
  const float* wdim  = (const float*)d_in[3];
  const float* bdim  = (const float*)d_in[4];
  const float* wpart = (const float*)d_in[5];
  const float* bpart = (const float*)d_in[6];
  float* out = (float*)d_out;

  // ---- workspace layout (bytes; ~70.3 MB total) ----
  char* W = (char*)d_ws;
  float* bl        = (float*)W;      W += 802816;     // [1000][200] f32
  _Float16* c1     = (_Float16*)W;   W += 458752;     // [1024][224]
  _Float16* c2     = (_Float16*)W;   W += 458752;
  _Float16* un1    = (_Float16*)W;   W += 6815744;    // [256][208][64]
  _Float16* un2    = (_Float16*)W;   W += 6815744;
  _Float16* ut1    = (_Float16*)W;   W += 7340032;    // [256][64][224]
  _Float16* ut2    = (_Float16*)W;   W += 7340032;
  float* h         = (float*)W;      W += 1048576;    // [256][1000] f32
  unsigned short* h_bf16 = (unsigned short*)W; W += 524288;   // [256][1024]
  float* part      = (float*)W;      W += 25600000;   // [32][1000][200] f32
  float* umap      = (float*)W;      W += 13107200;   // [256][200][64] f32

  hipMemcpyAsync(bl, rw, (size_t)HCN_ * L_ * sizeof(float),
                 hipMemcpyDeviceToDevice, stream);
  k_umap<<<800, 256, 0, stream>>>(u, lmap, umap);
  k_prep2<<<256, 256, 0, stream>>>(umap, un1, un2, ut1, ut2);

  // t = 0: no partials yet
  k_softmax2<0><<<256, 256, 0, stream>>>(bl, part, c1, c2);
  k_iter<1, 0><<<512, 256, 0, stream>>>(c1, c2, un1, un2, ut1, ut2,
                                        wdim, bdim, part, h);
  // t = 1: fold in t=0 partials
  k_softmax2<1><<<256, 256, 0, stream>>>(bl, part, c1, c2);
  k_iter<1, 0><<<512, 256, 0, stream>>>(c1, c2, un1, un2, ut1, ut2,
                                        wdim, bdim, part, h);
  // t = 2: fold in t=1 partials; emit h, no UV
  k_softmax2<1><<<256, 256, 0, stream>>>(bl, part, c1, c2);
  k_iter<0, 1><<<512, 256, 0, stream>>>(c1, c2, un1, un2, ut1, ut2,
                                        wdim, bdim, part, h);

  k_hcvt<<<256, 256, 0, stream>>>(h, h_bf16);
  k_out_mfma<<<dim3(157, 2), 512, 0, stream>>>(h_bf16, wpart, bpart, out);
}

// Round 8
// 477.204 us; speedup vs baseline: 1.6438x; 1.6438x over previous
//
#include <hip/hip_runtime.h>

#define B_    256
#define L_    200
#define EMB_  128
#define HD_   64
#define HCN_  1000
#define POI_  20000
#define EPS_  1e-8f
#define CP    224          // padded L for c / ut k-dim (7 chunks of 32)
#define UNR   208          // umap-native rows (l), rows 200..207 zero

// power-of-2 pre-scales keep fp16 second-splits in the normal range
#define CSC   16384.0f     // c scale (2^14)
#define USC   256.0f       // umap scale (2^8)
#define VSC   1024.0f      // v scale (2^10)
#define SV_DESC (1.0f / (CSC * USC))   // 2^-22, exact
#define UV_DESC (1.0f / (VSC * USC))   // 2^-18, exact

typedef _Float16 half8 __attribute__((ext_vector_type(8)));
typedef __bf16  bf16x8 __attribute__((ext_vector_type(8)));
typedef float   f32x4  __attribute__((ext_vector_type(4)));
typedef float   f32x16 __attribute__((ext_vector_type(16)));

__device__ __forceinline__ unsigned short f2bf(float f) {
  union { float f; unsigned int u; } v; v.f = f;
  unsigned int r = (v.u + 0x7FFFu + ((v.u >> 16) & 1u)) >> 16;  // RNE
  return (unsigned short)r;
}
// 2-way fp16 split of a PRE-SCALED value: x ~= s1+s2 to ~2^-22 relative
__device__ __forceinline__ void split2h(float x, _Float16& s1, _Float16& s2) {
  s1 = (_Float16)x;
  s2 = (_Float16)(x - (float)s1);
}

// 4-pass split product (keeps all cross terms; small-first accumulation)
#define FOURPASS(acc, A1f, A2f, B1f, B2f)                                  \
  acc = __builtin_amdgcn_mfma_f32_16x16x32_f16(A2f, B2f, acc, 0, 0, 0);    \
  acc = __builtin_amdgcn_mfma_f32_16x16x32_f16(A2f, B1f, acc, 0, 0, 0);    \
  acc = __builtin_amdgcn_mfma_f32_16x16x32_f16(A1f, B2f, acc, 0, 0, 0);    \
  acc = __builtin_amdgcn_mfma_f32_16x16x32_f16(A1f, B1f, acc, 0, 0, 0);

// ---------------------------------------------------------------------------
// k_umap: u_map[b,l,:] = u[b,l,:] @ l_map_h  (fp32 — routing precision source)
__global__ __launch_bounds__(256) void k_umap(const float* __restrict__ u,
                                              const float* __restrict__ lmap,
                                              float* __restrict__ umap) {
  __shared__ __align__(16) float lm[EMB_ * HD_];   // 32 KB
  for (int i = threadIdx.x; i < EMB_ * HD_; i += 256) lm[i] = lmap[i];
  __syncthreads();
  const int wave = threadIdx.x >> 6, lane = threadIdx.x & 63;
  const int wid = blockIdx.x * 4 + wave;
  for (int row = wid; row < B_ * L_; row += 3200) {
    const float* ur = u + (size_t)row * EMB_;
    float a0 = ur[lane];
    float a1 = ur[lane + 64];
    float acc = 0.f;
#pragma unroll
    for (int k = 0; k < 64; ++k)
      acc = fmaf(__shfl(a0, k), lm[k * HD_ + lane], acc);
#pragma unroll
    for (int k = 0; k < 64; ++k)
      acc = fmaf(__shfl(a1, k), lm[(k + 64) * HD_ + lane], acc);
    umap[(size_t)row * HD_ + lane] = acc;
  }
}

// ---------------------------------------------------------------------------
// k_prep2: umap[b] fp32 -> fp16 2-splits of (umap*USC), native [b][208][64]
// (rows 200..207 zero) and transposed [b][64][224] (cols 200..223 zero).
__global__ __launch_bounds__(256) void k_prep2(const float* __restrict__ umap,
    _Float16* __restrict__ un1, _Float16* __restrict__ un2,
    _Float16* __restrict__ ut1, _Float16* __restrict__ ut2) {
  __shared__ __align__(16) float us[CP][68];   // 60.9 KB
  const int b = blockIdx.x;
  const float* ub = umap + (size_t)b * L_ * HD_;
  for (int i = threadIdx.x; i < CP * HD_; i += 256) {
    int l = i >> 6, d = i & 63;
    us[l][d] = (l < L_) ? ub[l * HD_ + d] * USC : 0.f;
  }
  __syncthreads();
  // native: (row 208, oct 8)
  for (int s = threadIdx.x; s < UNR * 8; s += 256) {
    int row = s >> 3, oct = s & 7;
    _Float16 t1[8], t2[8];
#pragma unroll
    for (int j = 0; j < 8; ++j) split2h(us[row][oct * 8 + j], t1[j], t2[j]);
    size_t dst = ((size_t)b * UNR + row) * HD_ + oct * 8;
    *(uint4*)&un1[dst] = *(uint4*)t1;
    *(uint4*)&un2[dst] = *(uint4*)t2;
  }
  // transposed: (d 64, l-oct 28)
  for (int s = threadIdx.x; s < HD_ * 28; s += 256) {
    int d = s / 28, lo8 = s % 28;
    _Float16 t1[8], t2[8];
#pragma unroll
    for (int j = 0; j < 8; ++j) split2h(us[lo8 * 8 + j][d], t1[j], t2[j]);
    size_t dst = ((size_t)b * HD_ + d) * CP + lo8 * 8;
    *(uint4*)&ut1[dst] = *(uint4*)t1;
    *(uint4*)&ut2[dst] = *(uint4*)t2;
  }
}

// ---------------------------------------------------------------------------
// k_softmax2: c[row,:] = softmax(b[row,:]) -> fp16 2-splits of (c*CSC),
// [1024][224]; rows 1000..1023 and cols 200..223 exact zero.
__global__ __launch_bounds__(256) void k_softmax2(const float* __restrict__ bl,
    _Float16* __restrict__ c1, _Float16* __restrict__ c2) {
  const int wave = threadIdx.x >> 6, lane = threadIdx.x & 63;
  const int row = blockIdx.x * 4 + wave;                 // 0..1023
  const size_t rb = (size_t)row * CP;
  if (row >= HCN_) {
    c1[rb + lane] = (_Float16)0.f;       c2[rb + lane] = (_Float16)0.f;
    c1[rb + lane + 64] = (_Float16)0.f;  c2[rb + lane + 64] = (_Float16)0.f;
    c1[rb + lane + 128] = (_Float16)0.f; c2[rb + lane + 128] = (_Float16)0.f;
    if (lane < 32) { c1[rb + 192 + lane] = (_Float16)0.f; c2[rb + 192 + lane] = (_Float16)0.f; }
    return;
  }
  const float* br = bl + (size_t)row * L_;
  float x0 = br[lane];
  float x1 = br[lane + 64];
  float x2 = br[lane + 128];
  float x3 = (lane < 8) ? br[lane + 192] : -3.0e38f;
  float m = fmaxf(fmaxf(x0, x1), fmaxf(x2, x3));
#pragma unroll
  for (int off = 32; off; off >>= 1) m = fmaxf(m, __shfl_xor(m, off));
  float e0 = expf(x0 - m), e1 = expf(x1 - m), e2 = expf(x2 - m);
  float e3 = (lane < 8) ? expf(x3 - m) : 0.f;
  float ssum = e0 + e1 + e2 + e3;
#pragma unroll
  for (int off = 32; off; off >>= 1) ssum += __shfl_xor(ssum, off);
  float inv = CSC / ssum;
  _Float16 s1, s2;
  split2h(e0 * inv, s1, s2); c1[rb + lane] = s1;       c2[rb + lane] = s2;
  split2h(e1 * inv, s1, s2); c1[rb + lane + 64] = s1;  c2[rb + lane + 64] = s2;
  split2h(e2 * inv, s1, s2); c1[rb + lane + 128] = s1; c2[rb + lane + 128] = s2;
  if (lane < 8) {
    split2h(e3 * inv, s1, s2); c1[rb + 192 + lane] = s1; c2[rb + 192 + lane] = s2;
  } else if (lane < 32) {
    c1[rb + 192 + lane] = (_Float16)0.f; c2[rb + 192 + lane] = (_Float16)0.f;
  }
}

// ---------------------------------------------------------------------------
// k_iter: fused routing iteration, fp16 2-split / 4-pass, pre-scaled.
// Per block: 4 batches x 64 h-rows. LDS-staged operands (round-6 structure).
// Grid 1024: ht = id&15 (XCD = ht&7 -> atomic bl lines L2-local), bg = id>>4.
// HOUT writes h directly as padded bf16 [256][1024] (k_hcvt fused).
template<int UV, int HOUT>
__global__ __launch_bounds__(256, 2) void k_iter(
    const _Float16* __restrict__ c1p, const _Float16* __restrict__ c2p,
    const _Float16* __restrict__ un1, const _Float16* __restrict__ un2,
    const _Float16* __restrict__ ut1, const _Float16* __restrict__ ut2,
    const float* __restrict__ wdim, const float* __restrict__ bdim,
    float* __restrict__ bl, unsigned short* __restrict__ hb) {
  // union region: ut_s [2][2][64][40] (20,480 B) / un_s [2][208][40] (33,280 B)
  __shared__ __align__(16) _Float16 smem[16640];
  __shared__ __align__(16) _Float16 v_s[2][64][72];   // 18,432 B (split-indexed)
  typedef _Float16 (*UTarr)[2][64][40];
  typedef _Float16 (*UNarr)[208][40];
  UTarr UT = reinterpret_cast<UTarr>(smem);
  UNarr UN = reinterpret_cast<UNarr>(smem);

  const int id = blockIdx.x;
  const int ht = id & 15;         // XCD pin by ht: bl-row owners share an XCD
  const int bg = id >> 4;         // 0..63
  const int h0 = ht * 64;
  const int b0 = bg * 4;
  const int tid = threadIdx.x;
  const int wave = tid >> 6, lane = tid & 63;
  const int l15 = lane & 15, oc = lane >> 4;
  const int rowA = h0 + wave * 16 + l15;     // A-frag row (c row / v row)
  const int rowC = h0 + wave * 16 + oc * 4;  // C/D row base (+r)

#define STAGE_UT(cck, bf) {                                                    \
    const int d_ = tid >> 2, q_ = tid & 3;                                     \
    const size_t so_ = ((size_t)b * HD_ + d_) * CP + (cck) * 32 + q_ * 8;      \
    *(uint4*)&UT[bf][0][d_][q_ * 8] = *(const uint4*)&ut1[so_];                \
    *(uint4*)&UT[bf][1][d_][q_ * 8] = *(const uint4*)&ut2[so_];                \
  }

#define STAGE_UN(half_) {                                                      \
    _Pragma("unroll")                                                          \
    for (int j_ = 0; j_ < 4; ++j_) {                                           \
      int t_ = tid + 256 * j_;                                                 \
      if (t_ < 832) {                                                          \
        int row_ = t_ >> 2, q_ = t_ & 3;                                       \
        const size_t so_ = ((size_t)b * UNR + row_) * HD_ + (half_) * 32 + q_ * 8; \
        *(uint4*)&UN[0][row_][q_ * 8] = *(const uint4*)&un1[so_];              \
        *(uint4*)&UN[1][row_][q_ * 8] = *(const uint4*)&un2[so_];              \
      } } }

  // hoisted A fragments (c rows; invariant over the batches)
  half8 a_f[7][2];
#pragma unroll
  for (int ck = 0; ck < 7; ++ck) {
    const size_t off = (size_t)rowA * CP + ck * 32 + oc * 8;
    a_f[ck][0] = *(const half8*)&c1p[off];
    a_f[ck][1] = *(const half8*)&c2p[off];
  }

  f32x4 acc_uv[13];
  if (UV) {
#pragma unroll
    for (int nt = 0; nt < 13; ++nt) acc_uv[nt] = (f32x4){0.f, 0.f, 0.f, 0.f};
  }
  float wd[4] = {0.f, 0.f, 0.f, 0.f};
  float bd = 0.f;
  if (HOUT) {
#pragma unroll
    for (int nt = 0; nt < 4; ++nt) wd[nt] = wdim[nt * 16 + l15];
    bd = bdim[0];
  }

  for (int bi = 0; bi < 4; ++bi) {
    const int b = b0 + bi;
    // ---------------- SV: s = c @ umap[b] (scaled 2^22) ----------------
    f32x4 acc_s[4];
#pragma unroll
    for (int nt = 0; nt < 4; ++nt) acc_s[nt] = (f32x4){0.f, 0.f, 0.f, 0.f};
    STAGE_UT(0, 0);
    __syncthreads();
#pragma unroll
    for (int ck = 0; ck < 7; ++ck) {
      if (ck < 6) STAGE_UT(ck + 1, (ck + 1) & 1);
      const int cb = ck & 1;
#pragma unroll
      for (int nt = 0; nt < 4; ++nt) {
        const half8 b1 = *(const half8*)&UT[cb][0][nt * 16 + l15][oc * 8];
        const half8 b2 = *(const half8*)&UT[cb][1][nt * 16 + l15][oc * 8];
        FOURPASS(acc_s[nt], a_f[ck][0], a_f[ck][1], b1, b2);
      }
      __syncthreads();
    }
    // ---------------- squash (in-register, descaled) ----------------
    float xdesc[4][4];   // [nt][r]
#pragma unroll
    for (int nt = 0; nt < 4; ++nt)
#pragma unroll
      for (int r = 0; r < 4; ++r) xdesc[nt][r] = acc_s[nt][r] * SV_DESC;
    float gg[4], hq[4];
#pragma unroll
    for (int r = 0; r < 4; ++r) {
      float sq = 0.f, hpp = 0.f;
#pragma unroll
      for (int nt = 0; nt < 4; ++nt) {
        float x = xdesc[nt][r];
        sq += x * x;
        if (HOUT) hpp += x * wd[nt];
      }
#pragma unroll
      for (int off = 8; off; off >>= 1) {
        sq += __shfl_xor(sq, off);
        if (HOUT) hpp += __shfl_xor(hpp, off);
      }
      gg[r] = sq / ((1.f + sq) * sqrtf(sq + EPS_));
      if (HOUT) hq[r] = gg[r] * hpp + bd;
    }
    if (HOUT && l15 == 0) {
      // padded bf16 h write: rows >= 1000 exact zero (rowC is 4-aligned)
      ushort4 hv4;
      if (rowC < HCN_) {
        hv4.x = f2bf(hq[0]); hv4.y = f2bf(hq[1]);
        hv4.z = f2bf(hq[2]); hv4.w = f2bf(hq[3]);
      } else {
        hv4.x = hv4.y = hv4.z = hv4.w = 0;
      }
      *(ushort4*)&hb[(size_t)b * 1024 + rowC] = hv4;
    }
    // ---------------- UV: acc_uv += v @ umap[b]^T ----------------
    if (UV) {
#pragma unroll
      for (int nt = 0; nt < 4; ++nt)
#pragma unroll
        for (int r = 0; r < 4; ++r) {
          _Float16 s1, s2;
          split2h(VSC * gg[r] * xdesc[nt][r], s1, s2);
          const int vr = wave * 16 + oc * 4 + r, vc = nt * 16 + l15;
          v_s[0][vr][vc] = s1; v_s[1][vr][vc] = s2;
        }
      STAGE_UN(0);            // overlap un half-0 staging with v split/stores
      __syncthreads();
#pragma unroll
      for (int half = 0; half < 2; ++half) {
        if (half == 1) {
          STAGE_UN(1);
          __syncthreads();
        }
        const int vo = half * 32 + oc * 8;
        const half8 av1 = *(const half8*)&v_s[0][wave * 16 + l15][vo];
        const half8 av2 = *(const half8*)&v_s[1][wave * 16 + l15][vo];
#pragma unroll
        for (int nt = 0; nt < 13; ++nt) {
          const half8 b1 = *(const half8*)&UN[0][nt * 16 + l15][oc * 8];
          const half8 b2 = *(const half8*)&UN[1][nt * 16 + l15][oc * 8];
          FOURPASS(acc_uv[nt], av1, av2, b1, b2);
        }
        __syncthreads();
      }
    }
  }
  if (UV) {
#pragma unroll
    for (int nt = 0; nt < 13; ++nt)
#pragma unroll
      for (int r = 0; r < 4; ++r) {
        const int row = rowC + r, l = nt * 16 + l15;
        if (row < HCN_ && l < L_)
          atomicAdd(&bl[(size_t)row * L_ + l], acc_uv[nt][r] * UV_DESC);
      }
  }
#undef STAGE_UT
#undef STAGE_UN
}

// ---------------------------------------------------------------------------
// k_out_mfma: out[b,p] = sum_h h[b,h]*w_part[p,h] + b_part[p]  via bf16 MFMA.
#define KPAD 1024
#define LPITCH 72
__global__ __launch_bounds__(512) void k_out_mfma(const unsigned short* __restrict__ hb,
                                                  const float* __restrict__ wpart,
                                                  const float* __restrict__ bpart,
                                                  float* __restrict__ out) {
  __shared__ __align__(16) unsigned short w_lds[128 * LPITCH];  // 18432 B
  __shared__ __align__(16) unsigned short h_lds[128 * LPITCH];  // 18432 B
  const int p0 = blockIdx.x * 128;
  const int b0 = blockIdx.y * 128;
  const int t = threadIdx.x;
  const int wave = t >> 6, lane = t & 63;
  const int nt = wave & 3, mh = wave >> 2;
  const int l31 = lane & 31, lhi = lane >> 5;

  f32x16 acc0 = {};
  f32x16 acc1 = {};

  const int wrow = t >> 2;
  const int wq0  = (t & 3) * 4;
  int prow = p0 + wrow; if (prow > POI_ - 1) prow = POI_ - 1;
  const float* wrp = wpart + (size_t)prow * HCN_;

  for (int ch = 0; ch < 16; ++ch) {
    const int k0 = ch * 64;
    __syncthreads();
#pragma unroll
    for (int qq = 0; qq < 4; ++qq) {
      const int q = wq0 + qq;
      float4 wv;
      if (k0 + q * 4 + 3 < HCN_) {
        wv = *(const float4*)(wrp + k0 + q * 4);
      } else {
        float x0 = (k0 + q * 4 + 0 < HCN_) ? wrp[k0 + q * 4 + 0] : 0.f;
        float x1 = (k0 + q * 4 + 1 < HCN_) ? wrp[k0 + q * 4 + 1] : 0.f;
        float x2 = (k0 + q * 4 + 2 < HCN_) ? wrp[k0 + q * 4 + 2] : 0.f;
        float x3 = (k0 + q * 4 + 3 < HCN_) ? wrp[k0 + q * 4 + 3] : 0.f;
        wv = make_float4(x0, x1, x2, x3);
      }
      ushort4 bv;
      bv.x = f2bf(wv.x); bv.y = f2bf(wv.y); bv.z = f2bf(wv.z); bv.w = f2bf(wv.w);
      *(ushort4*)&w_lds[wrow * LPITCH + q * 4] = bv;
    }
#pragma unroll
    for (int n = 0; n < 2; ++n) {
      const int u = t + n * 512;
      const int hrow = u >> 3, hc = u & 7;
      const uint4 hv = *(const uint4*)(hb + (size_t)(b0 + hrow) * KPAD + k0 + hc * 8);
      *(uint4*)&h_lds[hrow * LPITCH + hc * 8] = hv;
    }
    __syncthreads();
#pragma unroll
    for (int ks = 0; ks < 4; ++ks) {
      const int kc = ks * 16 + lhi * 8;
      bf16x8 bfr = *(const bf16x8*)&w_lds[(nt * 32 + l31) * LPITCH + kc];
      bf16x8 a0  = *(const bf16x8*)&h_lds[(mh * 64 + 0 * 32 + l31) * LPITCH + kc];
      bf16x8 a1  = *(const bf16x8*)&h_lds[(mh * 64 + 1 * 32 + l31) * LPITCH + kc];
      acc0 = __builtin_amdgcn_mfma_f32_32x32x16_bf16(a0, bfr, acc0, 0, 0, 0);
      acc1 = __builtin_amdgcn_mfma_f32_32x32x16_bf16(a1, bfr, acc1, 0, 0, 0);
    }
  }

  const int p = p0 + nt * 32 + l31;
  const bool pok = (p < POI_);
  const float bp = pok ? bpart[p] : 0.f;
#pragma unroll
  for (int m = 0; m < 2; ++m) {
    const f32x16& a = m ? acc1 : acc0;
#pragma unroll
    for (int r = 0; r < 16; ++r) {
      const int brow = b0 + mh * 64 + m * 32 + (r & 3) + 8 * (r >> 2) + 4 * lhi;
      if (pok) out[(size_t)brow * POI_ + p] = a[r] + bp;
    }
  }
}

// ---------------------------------------------------------------------------
extern "C" void kernel_launch(void* const* d_in, const int* in_sizes, int n_in,
                              void* d_out, int out_size, void* d_ws, size_t ws_size,
                              hipStream_t stream) {
  const float* u     = (const float*)d_in[0];
  const float* lmap  = (const float*)d_in[1];
  const float* rw    = (const float*)d_in[2];
  const float* wdim  = (const float*)d_in[3];
  const float* bdim  = (const float*)d_in[4];
  const float* wpart = (const float*)d_in[5];
  const float* bpart = (const float*)d_in[6];
  float* out = (float*)d_out;

  // ---- workspace layout (bytes; ~44 MB total) ----
  char* W = (char*)d_ws;
  float* bl        = (float*)W;      W += 802816;     // [1000][200] f32
  _Float16* c1     = (_Float16*)W;   W += 458752;     // [1024][224]
  _Float16* c2     = (_Float16*)W;   W += 458752;
  _Float16* un1    = (_Float16*)W;   W += 6815744;    // [256][208][64]
  _Float16* un2    = (_Float16*)W;   W += 6815744;
  _Float16* ut1    = (_Float16*)W;   W += 7340032;    // [256][64][224]
  _Float16* ut2    = (_Float16*)W;   W += 7340032;
  unsigned short* h_bf16 = (unsigned short*)W; W += 524288;   // [256][1024]
  float* umap      = (float*)W;      W += 13107200;   // [256][200][64] f32

  hipMemcpyAsync(bl, rw, (size_t)HCN_ * L_ * sizeof(float),
                 hipMemcpyDeviceToDevice, stream);
  k_umap<<<800, 256, 0, stream>>>(u, lmap, umap);
  k_prep2<<<256, 256, 0, stream>>>(umap, un1, un2, ut1, ut2);

  for (int t = 0; t < 3; ++t) {
    k_softmax2<<<256, 256, 0, stream>>>(bl, c1, c2);
    if (t < 2)
      k_iter<1, 0><<<1024, 256, 0, stream>>>(c1, c2, un1, un2, ut1, ut2,
                                             wdim, bdim, bl, h_bf16);
    else
      k_iter<0, 1><<<1024, 256, 0, stream>>>(c1, c2, un1, un2, ut1, ut2,
                                             wdim, bdim, bl, h_bf16);
  }
  k_out_mfma<<<dim3(157, 2), 512, 0, stream>>>(h_bf16, wpart, bpart, out);
}

// Round 9
// 433.388 us; speedup vs baseline: 1.8100x; 1.1011x over previous
//
#include <hip/hip_runtime.h>

#define B_    256
#define L_    200
#define EMB_  128
#define HD_   64
#define HCN_  1000
#define POI_  20000
#define EPS_  1e-8f
#define CP    224          // padded L for c / ut k-dim (7 chunks of 32)
#define UNR   208          // umap-native rows (l), rows 200..207 zero

// power-of-2 pre-scales keep fp16 second-splits in the normal range
#define CSC   16384.0f     // c scale (2^14)
#define USC   256.0f       // umap scale (2^8)
#define VSC   1024.0f      // v scale (2^10)
#define SV_DESC (1.0f / (CSC * USC))   // 2^-22, exact
#define UV_DESC (1.0f / (VSC * USC))   // 2^-18, exact

typedef _Float16 half8 __attribute__((ext_vector_type(8)));
typedef __bf16  bf16x8 __attribute__((ext_vector_type(8)));
typedef float   f32x4  __attribute__((ext_vector_type(4)));
typedef float   f32x16 __attribute__((ext_vector_type(16)));

__device__ __forceinline__ unsigned short f2bf(float f) {
  union { float f; unsigned int u; } v; v.f = f;
  unsigned int r = (v.u + 0x7FFFu + ((v.u >> 16) & 1u)) >> 16;  // RNE
  return (unsigned short)r;
}
// 2-way fp16 split of a PRE-SCALED value: x ~= s1+s2 to ~2^-22 relative
__device__ __forceinline__ void split2h(float x, _Float16& s1, _Float16& s2) {
  s1 = (_Float16)x;
  s2 = (_Float16)(x - (float)s1);
}

// 4-pass split product (keeps all cross terms; small-first accumulation)
#define FOURPASS(acc, A1f, A2f, B1f, B2f)                                  \
  acc = __builtin_amdgcn_mfma_f32_16x16x32_f16(A2f, B2f, acc, 0, 0, 0);    \
  acc = __builtin_amdgcn_mfma_f32_16x16x32_f16(A2f, B1f, acc, 0, 0, 0);    \
  acc = __builtin_amdgcn_mfma_f32_16x16x32_f16(A1f, B2f, acc, 0, 0, 0);    \
  acc = __builtin_amdgcn_mfma_f32_16x16x32_f16(A1f, B1f, acc, 0, 0, 0);

// ---------------------------------------------------------------------------
// k_umap: u_map[b,l,:] = u[b,l,:] @ l_map_h  (fp32 — routing precision source)
__global__ __launch_bounds__(256) void k_umap(const float* __restrict__ u,
                                              const float* __restrict__ lmap,
                                              float* __restrict__ umap) {
  __shared__ __align__(16) float lm[EMB_ * HD_];   // 32 KB
  for (int i = threadIdx.x; i < EMB_ * HD_; i += 256) lm[i] = lmap[i];
  __syncthreads();
  const int wave = threadIdx.x >> 6, lane = threadIdx.x & 63;
  const int wid = blockIdx.x * 4 + wave;
  for (int row = wid; row < B_ * L_; row += 3200) {
    const float* ur = u + (size_t)row * EMB_;
    float a0 = ur[lane];
    float a1 = ur[lane + 64];
    float acc = 0.f;
#pragma unroll
    for (int k = 0; k < 64; ++k)
      acc = fmaf(__shfl(a0, k), lm[k * HD_ + lane], acc);
#pragma unroll
    for (int k = 0; k < 64; ++k)
      acc = fmaf(__shfl(a1, k), lm[(k + 64) * HD_ + lane], acc);
    umap[(size_t)row * HD_ + lane] = acc;
  }
}

// ---------------------------------------------------------------------------
// k_prep2: umap[b] fp32 -> fp16 2-splits of (umap*USC), native [b][208][64]
// (rows 200..207 zero) and transposed [b][64][224] (cols 200..223 zero).
__global__ __launch_bounds__(256) void k_prep2(const float* __restrict__ umap,
    _Float16* __restrict__ un1, _Float16* __restrict__ un2,
    _Float16* __restrict__ ut1, _Float16* __restrict__ ut2) {
  __shared__ __align__(16) float us[CP][68];   // 60.9 KB
  const int b = blockIdx.x;
  const float* ub = umap + (size_t)b * L_ * HD_;
  for (int i = threadIdx.x; i < CP * HD_; i += 256) {
    int l = i >> 6, d = i & 63;
    us[l][d] = (l < L_) ? ub[l * HD_ + d] * USC : 0.f;
  }
  __syncthreads();
  // native: (row 208, oct 8)
  for (int s = threadIdx.x; s < UNR * 8; s += 256) {
    int row = s >> 3, oct = s & 7;
    _Float16 t1[8], t2[8];
#pragma unroll
    for (int j = 0; j < 8; ++j) split2h(us[row][oct * 8 + j], t1[j], t2[j]);
    size_t dst = ((size_t)b * UNR + row) * HD_ + oct * 8;
    *(uint4*)&un1[dst] = *(uint4*)t1;
    *(uint4*)&un2[dst] = *(uint4*)t2;
  }
  // transposed: (d 64, l-oct 28)
  for (int s = threadIdx.x; s < HD_ * 28; s += 256) {
    int d = s / 28, lo8 = s % 28;
    _Float16 t1[8], t2[8];
#pragma unroll
    for (int j = 0; j < 8; ++j) split2h(us[lo8 * 8 + j][d], t1[j], t2[j]);
    size_t dst = ((size_t)b * HD_ + d) * CP + lo8 * 8;
    *(uint4*)&ut1[dst] = *(uint4*)t1;
    *(uint4*)&ut2[dst] = *(uint4*)t2;
  }
}

// ---------------------------------------------------------------------------
// k_softmax2: (SUM) fold 8 partial slabs into b[row,:] (write back, zero the
// slabs); then c[row,:] = softmax(b[row,:]) -> fp16 2-splits of (c*CSC),
// [1024][224]; rows 1000..1023 and cols 200..223 exact zero.
template<int SUM>
__global__ __launch_bounds__(256) void k_softmax2(float* __restrict__ bl,
    float* __restrict__ part,
    _Float16* __restrict__ c1, _Float16* __restrict__ c2) {
  const int wave = threadIdx.x >> 6, lane = threadIdx.x & 63;
  const int row = blockIdx.x * 4 + wave;                 // 0..1023
  const size_t rb = (size_t)row * CP;
  if (row >= HCN_) {
    c1[rb + lane] = (_Float16)0.f;       c2[rb + lane] = (_Float16)0.f;
    c1[rb + lane + 64] = (_Float16)0.f;  c2[rb + lane + 64] = (_Float16)0.f;
    c1[rb + lane + 128] = (_Float16)0.f; c2[rb + lane + 128] = (_Float16)0.f;
    if (lane < 32) { c1[rb + 192 + lane] = (_Float16)0.f; c2[rb + 192 + lane] = (_Float16)0.f; }
    return;
  }
  float* br = bl + (size_t)row * L_;
  float x0 = br[lane];
  float x1 = br[lane + 64];
  float x2 = br[lane + 128];
  float x3 = (lane < 8) ? br[lane + 192] : -3.0e38f;
  if (SUM) {
#pragma unroll
    for (int s = 0; s < 8; ++s) {
      float* p = part + ((size_t)s * HCN_ + row) * L_;
      x0 += p[lane];
      x1 += p[lane + 64];
      x2 += p[lane + 128];
      if (lane < 8) x3 += p[lane + 192];
      // zero the slab for the next k_iter (slab state self-restoring)
      p[lane] = 0.f; p[lane + 64] = 0.f; p[lane + 128] = 0.f;
      if (lane < 8) p[lane + 192] = 0.f;
    }
    br[lane] = x0; br[lane + 64] = x1; br[lane + 128] = x2;
    if (lane < 8) br[lane + 192] = x3;
  }
  float m = fmaxf(fmaxf(x0, x1), fmaxf(x2, x3));
#pragma unroll
  for (int off = 32; off; off >>= 1) m = fmaxf(m, __shfl_xor(m, off));
  float e0 = expf(x0 - m), e1 = expf(x1 - m), e2 = expf(x2 - m);
  float e3 = (lane < 8) ? expf(x3 - m) : 0.f;
  float ssum = e0 + e1 + e2 + e3;
#pragma unroll
  for (int off = 32; off; off >>= 1) ssum += __shfl_xor(ssum, off);
  float inv = CSC / ssum;
  _Float16 s1, s2;
  split2h(e0 * inv, s1, s2); c1[rb + lane] = s1;       c2[rb + lane] = s2;
  split2h(e1 * inv, s1, s2); c1[rb + lane + 64] = s1;  c2[rb + lane + 64] = s2;
  split2h(e2 * inv, s1, s2); c1[rb + lane + 128] = s1; c2[rb + lane + 128] = s2;
  if (lane < 8) {
    split2h(e3 * inv, s1, s2); c1[rb + 192 + lane] = s1; c2[rb + 192 + lane] = s2;
  } else if (lane < 32) {
    c1[rb + 192 + lane] = (_Float16)0.f; c2[rb + 192 + lane] = (_Float16)0.f;
  }
}

// ---------------------------------------------------------------------------
// k_iter: fused routing iteration, fp16 2-split / 4-pass, pre-scaled.
// Per block: 8 batches x 64 h-rows. LDS-staged operands (round-6 structure).
// Grid 512, decode bg=(id&7)+((id>>7)<<3), ht=(id>>3)&15: all 16 ht-blocks of
// one bg share id%8 (one XCD under round-robin) -> ut/un[b] fetched once per
// XCD (operand locality), and the UV partial slab part[bg&7] is XCD-local.
// HOUT writes h directly as padded bf16 [256][1024].
template<int UV, int HOUT>
__global__ __launch_bounds__(256, 2) void k_iter(
    const _Float16* __restrict__ c1p, const _Float16* __restrict__ c2p,
    const _Float16* __restrict__ un1, const _Float16* __restrict__ un2,
    const _Float16* __restrict__ ut1, const _Float16* __restrict__ ut2,
    const float* __restrict__ wdim, const float* __restrict__ bdim,
    float* __restrict__ part, unsigned short* __restrict__ hb) {
  // union region: ut_s [2][2][64][40] (20,480 B) / un_s [2][208][40] (33,280 B)
  __shared__ __align__(16) _Float16 smem[16640];
  __shared__ __align__(16) _Float16 v_s[2][64][72];   // 18,432 B (split-indexed)
  typedef _Float16 (*UTarr)[2][64][40];
  typedef _Float16 (*UNarr)[208][40];
  UTarr UT = reinterpret_cast<UTarr>(smem);
  UNarr UN = reinterpret_cast<UNarr>(smem);

  const int id = blockIdx.x;
  const int bg = (id & 7) + ((id >> 7) << 3);   // 0..31; bg%8 == id%8 (XCD)
  const int ht = (id >> 3) & 15;                // 0..15
  const int h0 = ht * 64;
  const int b0 = bg * 8;
  const int tid = threadIdx.x;
  const int wave = tid >> 6, lane = tid & 63;
  const int l15 = lane & 15, oc = lane >> 4;
  const int rowA = h0 + wave * 16 + l15;     // A-frag row (c row / v row)
  const int rowC = h0 + wave * 16 + oc * 4;  // C/D row base (+r)

#define STAGE_UT(cck, bf) {                                                    \
    const int d_ = tid >> 2, q_ = tid & 3;                                     \
    const size_t so_ = ((size_t)b * HD_ + d_) * CP + (cck) * 32 + q_ * 8;      \
    *(uint4*)&UT[bf][0][d_][q_ * 8] = *(const uint4*)&ut1[so_];                \
    *(uint4*)&UT[bf][1][d_][q_ * 8] = *(const uint4*)&ut2[so_];                \
  }

#define STAGE_UN(half_) {                                                      \
    _Pragma("unroll")                                                          \
    for (int j_ = 0; j_ < 4; ++j_) {                                           \
      int t_ = tid + 256 * j_;                                                 \
      if (t_ < 832) {                                                          \
        int row_ = t_ >> 2, q_ = t_ & 3;                                       \
        const size_t so_ = ((size_t)b * UNR + row_) * HD_ + (half_) * 32 + q_ * 8; \
        *(uint4*)&UN[0][row_][q_ * 8] = *(const uint4*)&un1[so_];              \
        *(uint4*)&UN[1][row_][q_ * 8] = *(const uint4*)&un2[so_];              \
      } } }

  // hoisted A fragments (c rows; invariant over the 8 batches)
  half8 a_f[7][2];
#pragma unroll
  for (int ck = 0; ck < 7; ++ck) {
    const size_t off = (size_t)rowA * CP + ck * 32 + oc * 8;
    a_f[ck][0] = *(const half8*)&c1p[off];
    a_f[ck][1] = *(const half8*)&c2p[off];
  }

  f32x4 acc_uv[13];
  if (UV) {
#pragma unroll
    for (int nt = 0; nt < 13; ++nt) acc_uv[nt] = (f32x4){0.f, 0.f, 0.f, 0.f};
  }
  float wd[4] = {0.f, 0.f, 0.f, 0.f};
  float bd = 0.f;
  if (HOUT) {
#pragma unroll
    for (int nt = 0; nt < 4; ++nt) wd[nt] = wdim[nt * 16 + l15];
    bd = bdim[0];
  }

  for (int bi = 0; bi < 8; ++bi) {
    const int b = b0 + bi;
    // ---------------- SV: s = c @ umap[b] (scaled 2^22) ----------------
    f32x4 acc_s[4];
#pragma unroll
    for (int nt = 0; nt < 4; ++nt) acc_s[nt] = (f32x4){0.f, 0.f, 0.f, 0.f};
    STAGE_UT(0, 0);
    __syncthreads();
#pragma unroll
    for (int ck = 0; ck < 7; ++ck) {
      if (ck < 6) STAGE_UT(ck + 1, (ck + 1) & 1);
      const int cb = ck & 1;
#pragma unroll
      for (int nt = 0; nt < 4; ++nt) {
        const half8 b1 = *(const half8*)&UT[cb][0][nt * 16 + l15][oc * 8];
        const half8 b2 = *(const half8*)&UT[cb][1][nt * 16 + l15][oc * 8];
        FOURPASS(acc_s[nt], a_f[ck][0], a_f[ck][1], b1, b2);
      }
      __syncthreads();
    }
    // ---------------- squash (in-register, descaled) ----------------
    float xdesc[4][4];   // [nt][r]
#pragma unroll
    for (int nt = 0; nt < 4; ++nt)
#pragma unroll
      for (int r = 0; r < 4; ++r) xdesc[nt][r] = acc_s[nt][r] * SV_DESC;
    float gg[4], hq[4];
#pragma unroll
    for (int r = 0; r < 4; ++r) {
      float sq = 0.f, hpp = 0.f;
#pragma unroll
      for (int nt = 0; nt < 4; ++nt) {
        float x = xdesc[nt][r];
        sq += x * x;
        if (HOUT) hpp += x * wd[nt];
      }
#pragma unroll
      for (int off = 8; off; off >>= 1) {
        sq += __shfl_xor(sq, off);
        if (HOUT) hpp += __shfl_xor(hpp, off);
      }
      gg[r] = sq / ((1.f + sq) * sqrtf(sq + EPS_));
      if (HOUT) hq[r] = gg[r] * hpp + bd;
    }
    if (HOUT && l15 == 0) {
      // padded bf16 h write: rows >= 1000 exact zero (rowC is 4-aligned)
      ushort4 hv4;
      if (rowC < HCN_) {
        hv4.x = f2bf(hq[0]); hv4.y = f2bf(hq[1]);
        hv4.z = f2bf(hq[2]); hv4.w = f2bf(hq[3]);
      } else {
        hv4.x = hv4.y = hv4.z = hv4.w = 0;
      }
      *(ushort4*)&hb[(size_t)b * 1024 + rowC] = hv4;
    }
    // ---------------- UV: acc_uv += v @ umap[b]^T ----------------
    if (UV) {
#pragma unroll
      for (int nt = 0; nt < 4; ++nt)
#pragma unroll
        for (int r = 0; r < 4; ++r) {
          _Float16 s1, s2;
          split2h(VSC * gg[r] * xdesc[nt][r], s1, s2);
          const int vr = wave * 16 + oc * 4 + r, vc = nt * 16 + l15;
          v_s[0][vr][vc] = s1; v_s[1][vr][vc] = s2;
        }
      __syncthreads();
#pragma unroll
      for (int half = 0; half < 2; ++half) {
        STAGE_UN(half);
        __syncthreads();
        const int vo = half * 32 + oc * 8;
        const half8 av1 = *(const half8*)&v_s[0][wave * 16 + l15][vo];
        const half8 av2 = *(const half8*)&v_s[1][wave * 16 + l15][vo];
#pragma unroll
        for (int nt = 0; nt < 13; ++nt) {
          const half8 b1 = *(const half8*)&UN[0][nt * 16 + l15][oc * 8];
          const half8 b2 = *(const half8*)&UN[1][nt * 16 + l15][oc * 8];
          FOURPASS(acc_uv[nt], av1, av2, b1, b2);
        }
        __syncthreads();
      }
    }
  }
  if (UV) {
    // XCD-local partial slab (slab index = bg&7 = id%8); 4-way contention max
    float* pp = part + (size_t)(bg & 7) * HCN_ * L_;
#pragma unroll
    for (int nt = 0; nt < 13; ++nt)
#pragma unroll
      for (int r = 0; r < 4; ++r) {
        const int row = rowC + r, l = nt * 16 + l15;
        if (row < HCN_ && l < L_)
          atomicAdd(&pp[(size_t)row * L_ + l], acc_uv[nt][r] * UV_DESC);
      }
  }
#undef STAGE_UT
#undef STAGE_UN
}

// ---------------------------------------------------------------------------
// k_out_mfma: out[b,p] = sum_h h[b,h]*w_part[p,h] + b_part[p]  via bf16 MFMA.
#define KPAD 1024
#define LPITCH 72
__global__ __launch_bounds__(512) void k_out_mfma(const unsigned short* __restrict__ hb,
                                                  const float* __restrict__ wpart,
                                                  const float* __restrict__ bpart,
                                                  float* __restrict__ out) {
  __shared__ __align__(16) unsigned short w_lds[128 * LPITCH];  // 18432 B
  __shared__ __align__(16) unsigned short h_lds[128 * LPITCH];  // 18432 B
  const int p0 = blockIdx.x * 128;
  const int b0 = blockIdx.y * 128;
  const int t = threadIdx.x;
  const int wave = t >> 6, lane = t & 63;
  const int nt = wave & 3, mh = wave >> 2;
  const int l31 = lane & 31, lhi = lane >> 5;

  f32x16 acc0 = {};
  f32x16 acc1 = {};

  const int wrow = t >> 2;
  const int wq0  = (t & 3) * 4;
  int prow = p0 + wrow; if (prow > POI_ - 1) prow = POI_ - 1;
  const float* wrp = wpart + (size_t)prow * HCN_;

  for (int ch = 0; ch < 16; ++ch) {
    const int k0 = ch * 64;
    __syncthreads();
#pragma unroll
    for (int qq = 0; qq < 4; ++qq) {
      const int q = wq0 + qq;
      float4 wv;
      if (k0 + q * 4 + 3 < HCN_) {
        wv = *(const float4*)(wrp + k0 + q * 4);
      } else {
        float x0 = (k0 + q * 4 + 0 < HCN_) ? wrp[k0 + q * 4 + 0] : 0.f;
        float x1 = (k0 + q * 4 + 1 < HCN_) ? wrp[k0 + q * 4 + 1] : 0.f;
        float x2 = (k0 + q * 4 + 2 < HCN_) ? wrp[k0 + q * 4 + 2] : 0.f;
        float x3 = (k0 + q * 4 + 3 < HCN_) ? wrp[k0 + q * 4 + 3] : 0.f;
        wv = make_float4(x0, x1, x2, x3);
      }
      ushort4 bv;
      bv.x = f2bf(wv.x); bv.y = f2bf(wv.y); bv.z = f2bf(wv.z); bv.w = f2bf(wv.w);
      *(ushort4*)&w_lds[wrow * LPITCH + q * 4] = bv;
    }
#pragma unroll
    for (int n = 0; n < 2; ++n) {
      const int u = t + n * 512;
      const int hrow = u >> 3, hc = u & 7;
      const uint4 hv = *(const uint4*)(hb + (size_t)(b0 + hrow) * KPAD + k0 + hc * 8);
      *(uint4*)&h_lds[hrow * LPITCH + hc * 8] = hv;
    }
    __syncthreads();
#pragma unroll
    for (int ks = 0; ks < 4; ++ks) {
      const int kc = ks * 16 + lhi * 8;
      bf16x8 bfr = *(const bf16x8*)&w_lds[(nt * 32 + l31) * LPITCH + kc];
      bf16x8 a0  = *(const bf16x8*)&h_lds[(mh * 64 + 0 * 32 + l31) * LPITCH + kc];
      bf16x8 a1  = *(const bf16x8*)&h_lds[(mh * 64 + 1 * 32 + l31) * LPITCH + kc];
      acc0 = __builtin_amdgcn_mfma_f32_32x32x16_bf16(a0, bfr, acc0, 0, 0, 0);
      acc1 = __builtin_amdgcn_mfma_f32_32x32x16_bf16(a1, bfr, acc1, 0, 0, 0);
    }
  }

  const int p = p0 + nt * 32 + l31;
  const bool pok = (p < POI_);
  const float bp = pok ? bpart[p] : 0.f;
#pragma unroll
  for (int m = 0; m < 2; ++m) {
    const f32x16& a = m ? acc1 : acc0;
#pragma unroll
    for (int r = 0; r < 16; ++r) {
      const int brow = b0 + mh * 64 + m * 32 + (r & 3) + 8 * (r >> 2) + 4 * lhi;
      if (pok) out[(size_t)brow * POI_ + p] = a[r] + bp;
    }
  }
}

// ---------------------------------------------------------------------------
extern "C" void kernel_launch(void* const* d_in, const int* in_sizes, int n_in,
                              void* d_out, int out_size, void* d_ws, size_t ws_size,
                              hipStream_t stream) {
  const float* u     = (const float*)d_in[0];
  const float* lmap  = (const float*)d_in[1];
  const float* rw    = (const float*)d_in[2];
  const float* wdim  = (const float*)d_in[3];
  const float* bdim  = (const float*)d_in[4];
  const float* wpart = (const float*)d_in[5];
  const float* bpart = (const float*)d_in[6];
  float* out = (float*)d_out;

  // ---- workspace layout (bytes; ~50 MB total) ----
  char* W = (char*)d_ws;
  float* bl        = (float*)W;      W += 802816;     // [1000][200] f32
  _Float16* c1     = (_Float16*)W;   W += 458752;     // [1024][224]
  _Float16* c2     = (_Float16*)W;   W += 458752;
  _Float16* un1    = (_Float16*)W;   W += 6815744;    // [256][208][64]
  _Float16* un2    = (_Float16*)W;   W += 6815744;
  _Float16* ut1    = (_Float16*)W;   W += 7340032;    // [256][64][224]
  _Float16* ut2    = (_Float16*)W;   W += 7340032;
  unsigned short* h_bf16 = (unsigned short*)W; W += 524288;   // [256][1024]
  float* part      = (float*)W;      W += 6400000;    // [8][1000][200] f32
  float* umap      = (float*)W;      W += 13107200;   // [256][200][64] f32

  hipMemcpyAsync(bl, rw, (size_t)HCN_ * L_ * sizeof(float),
                 hipMemcpyDeviceToDevice, stream);
  hipMemsetAsync(part, 0, 6400000, stream);
  k_umap<<<800, 256, 0, stream>>>(u, lmap, umap);
  k_prep2<<<256, 256, 0, stream>>>(umap, un1, un2, ut1, ut2);

  // t = 0: no partials yet
  k_softmax2<0><<<256, 256, 0, stream>>>(bl, part, c1, c2);
  k_iter<1, 0><<<512, 256, 0, stream>>>(c1, c2, un1, un2, ut1, ut2,
                                        wdim, bdim, part, h_bf16);
  // t = 1: fold in t=0 partials (and zero slabs)
  k_softmax2<1><<<256, 256, 0, stream>>>(bl, part, c1, c2);
  k_iter<1, 0><<<512, 256, 0, stream>>>(c1, c2, un1, un2, ut1, ut2,
                                        wdim, bdim, part, h_bf16);
  // t = 2: fold in t=1 partials; emit h, no UV
  k_softmax2<1><<<256, 256, 0, stream>>>(bl, part, c1, c2);
  k_iter<0, 1><<<512, 256, 0, stream>>>(c1, c2, un1, un2, ut1, ut2,
                                        wdim, bdim, part, h_bf16);

  k_out_mfma<<<dim3(157, 2), 512, 0, stream>>>(h_bf16, wpart, bpart, out);
}